// Round 6
// baseline (145.172 us; speedup 1.0000x reference)
//
#include <hip/hip_runtime.h>
#include <math.h>

typedef unsigned short u16;
typedef unsigned int u32;
typedef __attribute__((ext_vector_type(8))) short short8;
typedef __attribute__((ext_vector_type(8))) u16 u16x8;
typedef __attribute__((ext_vector_type(4))) float f32x4;

#define PH(i) ((i) + ((i) >> 6))

#if __has_builtin(__builtin_amdgcn_rcpf)
#define RCP(x) __builtin_amdgcn_rcpf(x)
#else
#define RCP(x) (1.0f / (x))
#endif

static __device__ __forceinline__ u16 f2bf(float x) {
  unsigned u = __builtin_bit_cast(unsigned, x);
  return (u16)((u + 0x7FFFu + ((u >> 16) & 1u)) >> 16);
}

static __device__ __forceinline__ float2 cmul(float2 a, float2 b) {
  return make_float2(a.x * b.x - a.y * b.y, a.x * b.y + a.y * b.x);
}
static __device__ __forceinline__ float2 cadd(float2 a, float2 b) {
  return make_float2(a.x + b.x, a.y + b.y);
}
static __device__ __forceinline__ float2 conjf2(float2 a) {
  return make_float2(a.x, -a.y);
}

// tanh-form GELU: y * sigmoid(1.59577*(y + 0.044715 y^3)); max dev ~1e-3
static __device__ __forceinline__ float gelu_fast(float y) {
  const float t = __builtin_fmaf(0.044715f * y * y, y, y);
  const float e = __expf(-1.5957691216f * t);
  return y * RCP(1.f + e);
}

// async global->LDS, 16B per lane
static __device__ __forceinline__ void gload_lds16(const void* g, void* l) {
  __builtin_amdgcn_global_load_lds(
      (const __attribute__((address_space(1))) u32*)g,
      (__attribute__((address_space(3))) u32*)l, 16, 0, 0);
}

// W_1024^e for e in [0,1024): 256-entry table + quadrant fixup
static __device__ __forceinline__ float2 twget(const float2* __restrict__ twl, int e) {
  float2 w = twl[e & 255];
  if (e & 256) w = make_float2(w.y, -w.x);   // * (-i)
  if (e & 512) w = make_float2(-w.x, -w.y);  // * (-1)
  return w;
}

// radix-4 DIF butterfly core (W = e^{-2pi i/N} convention)
#define BF4(A, B, C, D, Y0, Y1, Y2, Y3)                                        \
  {                                                                            \
    const float apcr = (A).x + (C).x, apci = (A).y + (C).y;                    \
    const float amcr = (A).x - (C).x, amci = (A).y - (C).y;                    \
    const float bpdr = (B).x + (D).x, bpdi = (B).y + (D).y;                    \
    const float bmdr = (B).x - (D).x, bmdi = (B).y - (D).y;                    \
    Y0 = make_float2(apcr + bpdr, apci + bpdi);                                \
    Y2 = make_float2(apcr - bpdr, apci - bpdi);                                \
    Y1 = make_float2(amcr + bmdi, amci - bmdr);                                \
    Y3 = make_float2(amcr - bmdi, amci + bmdr);                                \
  }

// ---------------- K1: ke[c,q] = (k[c,q]+conj(k[c,(2048-q)%2048]))/2 /2048
static __device__ __forceinline__ void hope_sum(
    const float* __restrict__ log_dt, const float* __restrict__ Hr,
    const float* __restrict__ Hi, int h, int l, float* outr, float* outi) {
  const float dt = expf(log_dt[h]);
  const float phi = 6.28318530717958647692f * (float)l * (1.0f / 1024.0f);
  float sphi, cphi;
  sincosf(phi, &sphi, &cphi);
  const float nr = (1.f + dt) * cphi + dt - 1.f;
  const float ni = (1.f + dt) * sphi;
  const float dr = (dt - 1.f) * cphi + dt + 1.f;
  const float di = (dt - 1.f) * sphi;
  const float theta = atan2f(ni * dr - nr * di, nr * dr + ni * di);
  float sw, cw;
  sincosf(theta, &sw, &cw);
  const float wr = cw, wi = -sw;  // e^{-i theta}
  float cr = wr, ci = wi;
  float ar = 0.f, ai = 0.f;
  const float* __restrict__ hr = Hr + h * 64;
  const float* __restrict__ hi = Hi + h * 64;
  for (int n = 0; n < 64; ++n) {
    const float a = hr[n], bb = hi[n];
    ar += a * cr - bb * ci;
    ai += a * ci + bb * cr;
    const float t = cr * wr - ci * wi;
    ci = cr * wi + ci * wr;
    cr = t;
  }
  *outr = ar;
  *outi = ai;
}

__global__ __launch_bounds__(256) void build_ke(
    const float* __restrict__ log_dt, const float* __restrict__ Hr,
    const float* __restrict__ Hi, float2* __restrict__ ke) {
  const int q = blockIdx.x * 256 + threadIdx.x;  // 0..1279
  const int c = blockIdx.y;
  if (q > 1024) return;
  float s1r = 0.f, s1i = 0.f, s2r = 0.f, s2i = 0.f;
  if (q <= 1023) hope_sum(log_dt, Hr, Hi, c, q, &s1r, &s1i);
  if (q >= 1) hope_sum(log_dt, Hr, Hi, c + 512, q - 1, &s2r, &s2i);
  float kr, ki;
  if (q == 0)         { kr = s1r; ki = 0.f; }
  else if (q == 1024) { kr = s2r; ki = 0.f; }
  else                { kr = 0.5f * (s1r + s2r); ki = 0.5f * (s1i - s2i); }
  const float s = 1.0f / 2048.0f;
  ke[c * 1026 + q] = make_float2(kr * s, ki * s);
}

// ---------------- K1b: fuse unpack*ke*repack into 4 coeffs per (c,f) ----------
// D[f] = C1*conj(Zf) + C2*Zg ; D[g] = C3*Zf + C4*conj(Zg), g = (1024-f)&1023
__global__ __launch_bounds__(256) void build_kep(
    const float2* __restrict__ ke, float2* __restrict__ kep) {
  const int q = blockIdx.x * 256 + threadIdx.x;  // 0..767
  const int c = blockIdx.y;
  if (q > 512) return;
  const float2 kf = ke[c * 1026 + q];
  const float2 kg = ke[c * 1026 + 1024 - q];
  float2 C1, C2, C3, C4;
  if (q == 0) {
    C1 = make_float2(kf.x + kg.x, kg.y - kf.y);        // conj(ke0)+keN
    C2 = make_float2(-(kg.y + kf.y), kg.x - kf.x);     // i*(keN-conj(ke0))
    C3 = C2;
    C4 = C1;
  } else {
    float st, ct;
    sincosf(3.14159265358979323846f * (float)q * (1.f / 1024.f), &st, &ct);
    const float2 A1 = make_float2(1.f - st, -ct);      // 1 - iW, W=ct-i*st
    const float2 A2 = make_float2(1.f + st, ct);       // 1 + iW
    const float2 kgc = make_float2(kg.x, -kg.y);
    const float2 t1 = cmul(kf, A1), t2 = cmul(kgc, A2);
    const float2 t3 = cmul(kf, A2), t4 = cmul(kgc, A1);
    const float2 p1 = make_float2(0.5f * (t1.x + t2.x), 0.5f * (t1.y + t2.y));
    const float2 p2 = make_float2(0.5f * (t3.x + t4.x), 0.5f * (t3.y + t4.y));
    const float2 q1 = make_float2(0.5f * (t1.x - t2.x), 0.5f * (t1.y - t2.y));
    const float2 q2 = make_float2(0.5f * (t3.x - t4.x), 0.5f * (t3.y - t4.y));
    const float2 iWc = make_float2(-st, ct);           // i*conj(W)
    const float2 r1 = cmul(iWc, q1), r2 = cmul(iWc, q2);
    C1 = make_float2(p1.x + r1.x, -(p1.y + r1.y));
    C2 = make_float2(p2.x + r2.x, -(p2.y + r2.y));
    C3 = make_float2(p1.x - r1.x, p1.y - r1.y);
    C4 = make_float2(p2.x - r2.x, p2.y - r2.y);
  }
  float2* o = kep + ((size_t)c * 513 + q) * 4;
  o[0] = C1; o[1] = C2; o[2] = C3; o[3] = C4;
}

// ---------------- in-place DIF trips (per-wave, no barriers) -------------------
// trip1: spans 256,64 fused (lane l owns {l+64a+256b})
static __device__ __forceinline__ void trip1_core(
    float2* __restrict__ dat, const float2* __restrict__ twl, int l,
    float2 v[4][4]) {
  float2 s1[4][4];
  #pragma unroll
  for (int a = 0; a < 4; ++a) {
    float2 y0, y1, y2, y3;
    BF4(v[0][a], v[1][a], v[2][a], v[3][a], y0, y1, y2, y3);
    const int e = l + 64 * a;
    s1[0][a] = y0;
    s1[1][a] = cmul(twget(twl, e), y1);
    s1[2][a] = cmul(twget(twl, 2 * e), y2);
    s1[3][a] = cmul(twget(twl, 3 * e), y3);
  }
  const float2 w1 = twget(twl, 4 * l);
  const float2 w2 = twget(twl, 8 * l);
  const float2 w3 = twget(twl, 12 * l);
  #pragma unroll
  for (int q = 0; q < 4; ++q) {
    float2 z0, z1, z2, z3;
    BF4(s1[q][0], s1[q][1], s1[q][2], s1[q][3], z0, z1, z2, z3);
    dat[PH(l + 256 * q)] = z0;
    dat[PH(l + 256 * q + 64)] = cmul(w1, z1);
    dat[PH(l + 256 * q + 128)] = cmul(w2, z2);
    dat[PH(l + 256 * q + 192)] = cmul(w3, z3);
  }
}

// trip2: spans 16,4 fused (lane l owns {64*(l>>2)+(l&3)+4a+16b})
static __device__ __forceinline__ void trip2(
    float2* __restrict__ dat, const float2* __restrict__ twl, int l) {
  const int p2 = l & 3;
  const int base = 64 * (l >> 2) + p2;
  float2 v[4][4];
  #pragma unroll
  for (int bq = 0; bq < 4; ++bq)
    #pragma unroll
    for (int a = 0; a < 4; ++a)
      v[bq][a] = dat[PH(base + 4 * a + 16 * bq)];
  float2 s1[4][4];
  #pragma unroll
  for (int a = 0; a < 4; ++a) {
    float2 y0, y1, y2, y3;
    BF4(v[0][a], v[1][a], v[2][a], v[3][a], y0, y1, y2, y3);
    const int e = 16 * (p2 + 4 * a);
    s1[0][a] = y0;
    s1[1][a] = cmul(twget(twl, e), y1);
    s1[2][a] = cmul(twget(twl, 2 * e), y2);
    s1[3][a] = cmul(twget(twl, 3 * e), y3);
  }
  const float2 w1 = twget(twl, 64 * p2);
  const float2 w2 = twget(twl, 128 * p2);
  const float2 w3 = twget(twl, 192 * p2);
  #pragma unroll
  for (int q = 0; q < 4; ++q) {
    float2 z0, z1, z2, z3;
    BF4(s1[q][0], s1[q][1], s1[q][2], s1[q][3], z0, z1, z2, z3);
    dat[PH(base + 16 * q)] = z0;
    dat[PH(base + 16 * q + 4)] = cmul(w1, z1);
    dat[PH(base + 16 * q + 8)] = cmul(w2, z2);
    dat[PH(base + 16 * q + 12)] = cmul(w3, z3);
  }
}

// trip3: span 1 (no twiddles); lane l owns blocks B = l+64j
static __device__ __forceinline__ void trip3(float2* __restrict__ dat, int l) {
  #pragma unroll
  for (int j = 0; j < 4; ++j) {
    const int B4 = 4 * (l + 64 * j);
    const float2 a = dat[PH(B4)], b = dat[PH(B4 + 1)];
    const float2 c = dat[PH(B4 + 2)], d = dat[PH(B4 + 3)];
    float2 y0, y1, y2, y3;
    BF4(a, b, c, d, y0, y1, y2, y3);
    dat[PH(B4)] = y0; dat[PH(B4 + 1)] = y1;
    dat[PH(B4 + 2)] = y2; dat[PH(B4 + 3)] = y3;
  }
}

// ---------------- K2: wave-autonomous rfft-conv + D-skip + GELU -> bf16 y -----
__global__ __launch_bounds__(256) void fft_conv(
    const float* __restrict__ u, const float2* __restrict__ kep,
    const float* __restrict__ Dv, u16* __restrict__ y) {
  __shared__ float2 data_s[4][1040];
  __shared__ float2 twl[256];
  const int tid = threadIdx.x;
  {
    float s, cc;
    __sincosf(6.28318530717958647692f * (float)tid * (1.f / 1024.f), &s, &cc);
    twl[tid] = make_float2(cc, -s);
  }
  __syncthreads();  // only barrier: twl visible to all waves

  const int w = tid >> 6, l = tid & 63;
  const int b = blockIdx.x * 4 + w, c = blockIdx.y;
  float2* __restrict__ dat = data_s[w];
  const float* __restrict__ urow = u + ((size_t)(b * 512 + c)) * 2048;
  const float2* __restrict__ u2 = (const float2*)urow;

  // FFT #1 (forward, packed z = u_even + i*u_odd), trip1 reads global
  {
    float2 v[4][4];
    #pragma unroll
    for (int bq = 0; bq < 4; ++bq)
      #pragma unroll
      for (int a = 0; a < 4; ++a)
        v[bq][a] = u2[l + 64 * a + 256 * bq];
    trip1_core(dat, twl, l, v);
  }
  trip2(dat, twl, l);
  trip3(dat, l);

  // filter: array holds Z[rev(i)] at i; write D (=conj(Z')) at natural pos
  const int r3 = 16 * (l & 3) + 4 * ((l >> 2) & 3) + (l >> 4);   // rev3(l)
  const int lg = (64 - l) & 63;
  const int r3g = 16 * (lg & 3) + 4 * ((lg >> 2) & 3) + (lg >> 4);
  const float2* __restrict__ krow = kep + (size_t)c * (513 * 4);
  {
    float2 Zf[8], Zg[8];
    #pragma unroll
    for (int j = 0; j < 8; ++j) {
      const int rf = 16 * r3 + 4 * (j & 3) + (j >> 2);
      const int jg = ((l == 0) ? (16 - j) : (15 - j)) & 15;
      const int rg = 16 * r3g + 4 * (jg & 3) + (jg >> 2);
      Zf[j] = dat[PH(rf)];
      Zg[j] = dat[PH(rg)];
    }
    const float2 Z5 = dat[PH(2)];  // rev(512) = 2
    #pragma unroll
    for (int j = 0; j < 8; ++j) {
      const int f = l + 64 * j;
      const int gm = (1024 - f) & 1023;
      const float2 C1 = krow[f * 4 + 0], C2 = krow[f * 4 + 1];
      const float2 C3 = krow[f * 4 + 2], C4 = krow[f * 4 + 3];
      dat[PH(f)] = cadd(cmul(C1, conjf2(Zf[j])), cmul(C2, Zg[j]));
      dat[PH(gm)] = cadd(cmul(C3, Zf[j]), cmul(C4, conjf2(Zg[j])));
    }
    if (l == 0) {
      const float2 C1 = krow[512 * 4 + 0], C2 = krow[512 * 4 + 1];
      dat[PH(512)] = cadd(cmul(C1, conjf2(Z5)), cmul(C2, Z5));
    }
  }

  // FFT #2 (same forward DIF on conj data = inverse via conj trick)
  {
    float2 v[4][4];
    #pragma unroll
    for (int bq = 0; bq < 4; ++bq)
      #pragma unroll
      for (int a = 0; a < 4; ++a)
        v[bq][a] = dat[PH(l + 64 * a + 256 * bq)];
    trip1_core(dat, twl, l, v);
  }
  trip2(dat, twl, l);
  trip3(dat, l);

  // output: time t at position rev(t); lane l covers t_pack in [16l,16l+16)
  const float Dc = Dv[c];
  const float4* __restrict__ u4 = (const float4*)urow + 8 * l;
  u16 ov[32];
  #pragma unroll
  for (int i2 = 0; i2 < 8; ++i2) {
    const float4 uu = u4[i2];
    const int i0 = 2 * i2, i1 = 2 * i2 + 1;
    const float2 ra = dat[PH(256 * (i0 & 3) + 64 * (i0 >> 2) + r3)];
    const float2 rb = dat[PH(256 * (i1 & 3) + 64 * (i1 >> 2) + r3)];
    const float ye0 = ra.x + uu.x * Dc, yo0 = -ra.y + uu.y * Dc;
    const float ye1 = rb.x + uu.z * Dc, yo1 = -rb.y + uu.w * Dc;
    ov[4 * i2 + 0] = f2bf(gelu_fast(ye0));
    ov[4 * i2 + 1] = f2bf(gelu_fast(yo0));
    ov[4 * i2 + 2] = f2bf(gelu_fast(ye1));
    ov[4 * i2 + 3] = f2bf(gelu_fast(yo1));
  }
  u16* __restrict__ yrow = y + ((size_t)(b * 512 + c)) * 2048 + 32 * l;
  #pragma unroll
  for (int s = 0; s < 4; ++s)
    *(u16x8*)(yrow + 8 * s) = *(u16x8*)(ov + 8 * s);
}

// ---------------- K2b: y (B,C,L) bf16 -> yt (B,L,C) bf16 ----------------
__global__ __launch_bounds__(256) void transpose_y(
    const u16* __restrict__ y, u16* __restrict__ yt) {
  __shared__ u16 tile[64][80];
  const int b = blockIdx.z;
  const int tb = blockIdx.x * 64;
  const int cb = blockIdx.y * 64;
  const int tid = threadIdx.x;
  {
    const int tl = (tid & 7) * 8;
    const int cl = tid >> 3;
    #pragma unroll
    for (int h = 0; h < 2; ++h) {
      const int cc = cl + h * 32;
      const u16x8 v = *(const u16x8*)(y + ((size_t)(b * 512 + cb + cc)) * 2048 + tb + tl);
      #pragma unroll
      for (int i = 0; i < 8; ++i) tile[cc][tl + i] = v[i];
    }
  }
  __syncthreads();
  {
    const int c2 = (tid & 7) * 8;
    const int t2 = tid >> 3;
    #pragma unroll
    for (int h = 0; h < 2; ++h) {
      const int tt = t2 + h * 32;
      u16 tmp[8];
      #pragma unroll
      for (int i = 0; i < 8; ++i) tmp[i] = tile[c2 + i][tt];
      *(u16x8*)(yt + ((size_t)(b * 2048 + tb + tt)) * 512 + cb + c2) = *(u16x8*)tmp;
    }
  }
}

// ---------------- K2c: W f32 -> bf16 ----------------
__global__ __launch_bounds__(256) void conv_w(const float* __restrict__ W,
                                              u16* __restrict__ Wb) {
  const int i = blockIdx.x * 256 + threadIdx.x;
  Wb[i] = f2bf(W[i]);
}

// ---------------- K3: 256x256x(K=512) 8-phase GEMM + GLU ----------------
#define FRAG_A(P, MI, S) __builtin_bit_cast(short8, *(const u16x8*)&lds[       \
    (P) * 16384 + wmh + ((MI) * 16 + lrow) * 64 + ((S) ? cs1 : cs0)])
#define FRAG_B(P, NI, S) __builtin_bit_cast(short8, *(const u16x8*)&lds[       \
    32768 + (P) * 16384 + hBh + (rB + (NI) * 16 + lrow) * 64 + ((S) ? cs1 : cs0)])

#define STAGE_A(KT, H, P) do {                                                 \
    int sr_ = m0 + (H) * 128 + wq8 + l3;                                       \
    int o0_ = (sr_ & 1) ? (512 + (sr_ >> 1)) : (sr_ >> 1);                     \
    gload_lds16(Wb + (size_t)o0_ * 512 + (KT) * 64 + csw,                      \
                lds + (P) * 16384 + (H) * 8192 + wq * 512);                    \
    sr_ += 64;                                                                 \
    int o1_ = (sr_ & 1) ? (512 + (sr_ >> 1)) : (sr_ >> 1);                     \
    gload_lds16(Wb + (size_t)o1_ * 512 + (KT) * 64 + csw,                      \
                lds + (P) * 16384 + (H) * 8192 + 4096 + wq * 512);             \
  } while (0)
#define STAGE_B(KT, H, P) do {                                                 \
    int tr_ = t0b + (H) * 128 + wq8 + l3;                                      \
    gload_lds16(yt + ((size_t)(bb * 2048 + tr_)) * 512 + (KT) * 64 + csw,      \
                lds + 32768 + (P) * 16384 + (H) * 8192 + wq * 512);            \
    gload_lds16(yt + ((size_t)(bb * 2048 + tr_ + 64)) * 512 + (KT) * 64 + csw, \
                lds + 32768 + (P) * 16384 + (H) * 8192 + 4096 + wq * 512);     \
  } while (0)

#define MFMA2(MI, NI, A0, A1)                                                  \
    acc[MI][NI] = __builtin_amdgcn_mfma_f32_16x16x32_bf16(A0, br[NI][0],       \
                                                          acc[MI][NI], 0, 0, 0); \
    acc[MI][NI] = __builtin_amdgcn_mfma_f32_16x16x32_bf16(A1, br[NI][1],       \
                                                          acc[MI][NI], 0, 0, 0);

#define PHASE_CORE(Q, READS, STAGES, VWAIT)                                    \
  {                                                                            \
    short8 a00 = FRAG_A(PP, (Q)*2 + 0, 0), a01 = FRAG_A(PP, (Q)*2 + 0, 1);     \
    short8 a10 = FRAG_A(PP, (Q)*2 + 1, 0), a11 = FRAG_A(PP, (Q)*2 + 1, 1);     \
    READS;                                                                     \
    STAGES;                                                                    \
    __builtin_amdgcn_s_barrier();                                              \
    asm volatile("s_waitcnt lgkmcnt(0)" ::: "memory");                         \
    __builtin_amdgcn_sched_barrier(0);                                         \
    __builtin_amdgcn_s_setprio(1);                                             \
    MFMA2((Q)*2 + 0, 0, a00, a01) MFMA2((Q)*2 + 0, 1, a00, a01)                \
    MFMA2((Q)*2 + 0, 2, a00, a01) MFMA2((Q)*2 + 0, 3, a00, a01)                \
    MFMA2((Q)*2 + 1, 0, a10, a11) MFMA2((Q)*2 + 1, 1, a10, a11)                \
    MFMA2((Q)*2 + 1, 2, a10, a11) MFMA2((Q)*2 + 1, 3, a10, a11)                \
    __builtin_amdgcn_s_setprio(0);                                             \
    __builtin_amdgcn_sched_barrier(0);                                         \
    VWAIT;                                                                     \
    __builtin_amdgcn_s_barrier();                                              \
  }

#define READ_B(P) do {                                                         \
    br[0][0] = FRAG_B(P, 0, 0); br[0][1] = FRAG_B(P, 0, 1);                    \
    br[1][0] = FRAG_B(P, 1, 0); br[1][1] = FRAG_B(P, 1, 1);                    \
    br[2][0] = FRAG_B(P, 2, 0); br[2][1] = FRAG_B(P, 2, 1);                    \
    br[3][0] = FRAG_B(P, 3, 0); br[3][1] = FRAG_B(P, 3, 1);                    \
  } while (0)

__global__ __launch_bounds__(512, 2) void gemm_glu(
    const u16* __restrict__ Wb, const u16* __restrict__ yt,
    const float* __restrict__ bias, float* __restrict__ out) {
  extern __shared__ __align__(16) u16 lds[];
  const int bid = blockIdx.x;
  const int wg = (bid & 7) * 64 + (bid >> 3);  // XCD swizzle (512 = 8*64)
  const int bb = wg >> 5;
  const int mt = (wg >> 3) & 3;
  const int nt = wg & 7;
  const int m0 = mt * 256;
  const int t0b = nt * 256;
  const int tid = threadIdx.x;
  const int lane = tid & 63;
  const int wq = tid >> 6;
  const int wq8 = wq * 8, l3 = lane >> 3;
  const int wm = wq >> 2, wn = wq & 3;
  const int lrow = lane & 15, lq = lane >> 4;
  const int csw = ((lane & 7) ^ l3) * 8;
  const int cs0 = ((lq ^ (lane & 7)) << 3);
  const int cs1 = (((4 + lq) ^ (lane & 7)) << 3);
  const int wmh = wm * 8192;
  const int hBh = (wn >> 1) * 8192;
  const int rB = (wn & 1) * 64;

  f32x4 acc[8][4];
  const f32x4 z4 = {0.f, 0.f, 0.f, 0.f};
  #pragma unroll
  for (int mi = 0; mi < 8; ++mi)
    #pragma unroll
    for (int ni = 0; ni < 4; ++ni) acc[mi][ni] = z4;
  short8 br[4][2];

  STAGE_A(0, 0, 0); STAGE_A(0, 1, 0);
  STAGE_B(0, 0, 0); STAGE_B(0, 1, 0);
  STAGE_B(1, 0, 1); STAGE_B(1, 1, 1);
  asm volatile("s_waitcnt vmcnt(4)" ::: "memory");
  __builtin_amdgcn_s_barrier();

  #pragma unroll
  for (int j = 0; j < 4; ++j) {
    const int e2 = 2 * j + 2, o1 = 2 * j + 1, o3 = 2 * j + 3;
    #define PP 0
    PHASE_CORE(0, READ_B(0), STAGE_A(o1, 0, 1), )
    PHASE_CORE(1, , { STAGE_A(o1, 1, 1); if (j < 3) STAGE_B(e2, 0, 0); }, )
    PHASE_CORE(2, , if (j < 3) STAGE_B(e2, 1, 0), )
    PHASE_CORE(3, , ,
               if (j < 3) { asm volatile("s_waitcnt vmcnt(4)" ::: "memory"); }
               else { asm volatile("s_waitcnt vmcnt(0)" ::: "memory"); })
    #undef PP
    #define PP 1
    PHASE_CORE(0, READ_B(1), if (j < 3) STAGE_A(e2, 0, 0), )
    PHASE_CORE(1, , if (j < 3) STAGE_A(e2, 1, 0), )
    PHASE_CORE(2, , if (j < 3) STAGE_B(o3, 0, 1), )
    PHASE_CORE(3, , if (j < 3) STAGE_B(o3, 1, 1),
               if (j < 3) { asm volatile("s_waitcnt vmcnt(4)" ::: "memory"); })
    #undef PP
  }

  #pragma unroll
  for (int mi = 0; mi < 8; ++mi) {
    const int sr0 = m0 + wm * 128 + mi * 16 + lq * 4;
    const int ch = sr0 >> 1;
    const float ba0 = bias[ch],     bg0 = bias[512 + ch];
    const float ba1 = bias[ch + 1], bg1 = bias[512 + ch + 1];
    #pragma unroll
    for (int ni = 0; ni < 4; ++ni) {
      const int t = t0b + wn * 64 + ni * 16 + (lane & 15);
      const f32x4 v = acc[mi][ni];
      const float a0 = v[0] + ba0, g0 = v[1] + bg0;
      const float a1 = v[2] + ba1, g1 = v[3] + bg1;
      out[((size_t)(bb * 512 + ch)) * 2048 + t]     = a0 * RCP(1.f + __expf(-g0));
      out[((size_t)(bb * 512 + ch + 1)) * 2048 + t] = a1 * RCP(1.f + __expf(-g1));
    }
  }
}

extern "C" void kernel_launch(void* const* d_in, const int* in_sizes, int n_in,
                              void* d_out, int out_size, void* d_ws, size_t ws_size,
                              hipStream_t stream) {
  (void)in_sizes; (void)n_in; (void)out_size; (void)ws_size;
  const float* u      = (const float*)d_in[0];
  const float* log_dt = (const float*)d_in[1];
  const float* Hr     = (const float*)d_in[2];
  const float* Hi     = (const float*)d_in[3];
  const float* Dv     = (const float*)d_in[4];
  const float* W      = (const float*)d_in[5];
  const float* bias   = (const float*)d_in[6];

  char* ws = (char*)d_ws;
  float2* ke = (float2*)(ws);                      // 4.2 MB
  u16*    Wb = (u16*)  (ws + ((size_t)5 << 20));   // 1 MB
  u16*    yt = (u16*)  (ws + ((size_t)8 << 20));   // 32 MB
  u16*    ybf = (u16*)d_out;                       // bf16 y staged in d_out[0,32MB)
  float2* kep = (float2*)((char*)d_out + ((size_t)32 << 20));  // 8.4 MB scratch

  build_ke<<<dim3(5, 512), 256, 0, stream>>>(log_dt, Hr, Hi, ke);
  build_kep<<<dim3(3, 512), 256, 0, stream>>>(ke, kep);
  conv_w<<<dim3(2048), 256, 0, stream>>>(W, Wb);
  fft_conv<<<dim3(4, 512), 256, 0, stream>>>(u, kep, Dv, ybf);
  transpose_y<<<dim3(32, 8, 16), 256, 0, stream>>>(ybf, yt);
  gemm_glu<<<dim3(512), 512, 131072, stream>>>(Wb, yt, bias, (float*)d_out);
}

// Round 7
// 135.682 us; speedup vs baseline: 1.0699x; 1.0699x over previous
//
#include <hip/hip_runtime.h>
#include <math.h>

typedef unsigned short u16;
typedef unsigned int u32;
typedef __attribute__((ext_vector_type(8))) short short8;
typedef __attribute__((ext_vector_type(8))) u16 u16x8;
typedef __attribute__((ext_vector_type(4))) float f32x4;

#define PHYS(i) ((i) + ((i) >> 4))

#if __has_builtin(__builtin_amdgcn_rcpf)
#define RCP(x) __builtin_amdgcn_rcpf(x)
#else
#define RCP(x) (1.0f / (x))
#endif

static __device__ __forceinline__ u16 f2bf(float x) {
  unsigned u = __builtin_bit_cast(unsigned, x);
  return (u16)((u + 0x7FFFu + ((u >> 16) & 1u)) >> 16);
}

static __device__ __forceinline__ float2 cmul(float2 a, float2 b) {
  return make_float2(a.x * b.x - a.y * b.y, a.x * b.y + a.y * b.x);
}
static __device__ __forceinline__ float2 cadd(float2 a, float2 b) {
  return make_float2(a.x + b.x, a.y + b.y);
}
static __device__ __forceinline__ float2 conjf2(float2 a) {
  return make_float2(a.x, -a.y);
}

// tanh-form GELU: y * sigmoid(1.59577*(y + 0.044715 y^3)); max dev ~1e-3
static __device__ __forceinline__ float gelu_fast(float y) {
  const float t = __builtin_fmaf(0.044715f * y * y, y, y);
  const float e = __expf(-1.5957691216f * t);
  return y * RCP(1.f + e);
}

// async global->LDS, 16B per lane
static __device__ __forceinline__ void gload_lds16(const void* g, void* l) {
  __builtin_amdgcn_global_load_lds(
      (const __attribute__((address_space(1))) u32*)g,
      (__attribute__((address_space(3))) u32*)l, 16, 0, 0);
}

// ---------------- K1: merged hope-kernel + filter-coefficient build ------------
// K[h,l] = sum_n (Hr+iHi)[h,n] * exp(-i*theta(h,l)*(n+1))
static __device__ __forceinline__ void hope_sum(
    const float* __restrict__ log_dt, const float* __restrict__ Hr,
    const float* __restrict__ Hi, int h, int l, float* outr, float* outi) {
  const float dt = expf(log_dt[h]);
  const float phi = 6.28318530717958647692f * (float)l * (1.0f / 1024.0f);
  float sphi, cphi;
  sincosf(phi, &sphi, &cphi);
  const float nr = (1.f + dt) * cphi + dt - 1.f;
  const float ni = (1.f + dt) * sphi;
  const float dr = (dt - 1.f) * cphi + dt + 1.f;
  const float di = (dt - 1.f) * sphi;
  const float theta = atan2f(ni * dr - nr * di, nr * dr + ni * di);
  float sw, cw;
  sincosf(theta, &sw, &cw);
  const float wr = cw, wi = -sw;  // e^{-i theta}
  float cr = wr, ci = wi;
  float ar = 0.f, ai = 0.f;
  const float* __restrict__ hr = Hr + h * 64;
  const float* __restrict__ hi = Hi + h * 64;
  for (int n = 0; n < 64; ++n) {
    const float a = hr[n], bb = hi[n];
    ar += a * cr - bb * ci;
    ai += a * ci + bb * cr;
    const float t = cr * wr - ci * wi;
    ci = cr * wi + ci * wr;
    cr = t;
  }
  *outr = ar;
  *outi = ai;
}

// One block per channel c. K1[l]=K[c,l], K2[l]=K[c+512,l] staged in LDS, then
// kep[c,q]*4 coeffs: D[f]=C1*conj(Zf)+C2*Zg ; D[g]=C3*Zf+C4*conj(Zg).
__global__ __launch_bounds__(512) void build_kep(
    const float* __restrict__ log_dt, const float* __restrict__ Hr,
    const float* __restrict__ Hi, float2* __restrict__ kep) {
  __shared__ float2 K1[1024], K2[1024];
  const int c = blockIdx.x;
  const int t = threadIdx.x;
  float r, i;
  hope_sum(log_dt, Hr, Hi, c, t, &r, &i);             K1[t] = make_float2(r, i);
  hope_sum(log_dt, Hr, Hi, c, t + 512, &r, &i);       K1[t + 512] = make_float2(r, i);
  hope_sum(log_dt, Hr, Hi, c + 512, t, &r, &i);       K2[t] = make_float2(r, i);
  hope_sum(log_dt, Hr, Hi, c + 512, t + 512, &r, &i); K2[t + 512] = make_float2(r, i);
  __syncthreads();
  const float s = 1.0f / 2048.0f;  // fold ifft scale (exact)
  for (int q = t; q <= 512; q += 512) {  // t==0 also covers q=512
    // ke(q) = (k[c,q]+conj(k[c,(2048-q)%2048]))/2 * s
    float2 kf, kg;
    {
      const int qa = q;
      kf = (qa == 0) ? make_float2(K1[0].x * s, 0.f)
                     : make_float2(0.5f * s * (K1[qa].x + K2[qa - 1].x),
                                   0.5f * s * (K1[qa].y - K2[qa - 1].y));
      const int qb = 1024 - q;
      kg = (qb == 1024) ? make_float2(K2[1023].x * s, 0.f)
           : (qb == 0)  ? make_float2(K1[0].x * s, 0.f)
                        : make_float2(0.5f * s * (K1[qb].x + K2[qb - 1].x),
                                      0.5f * s * (K1[qb].y - K2[qb - 1].y));
    }
    float2 C1, C2, C3, C4;
    if (q == 0) {
      C1 = make_float2(kf.x + kg.x, kg.y - kf.y);     // conj(ke0)+keN
      C2 = make_float2(-(kg.y + kf.y), kg.x - kf.x);  // i*(keN-conj(ke0))
      C3 = C2;
      C4 = C1;
    } else {
      float st, ct;
      sincosf(3.14159265358979323846f * (float)q * (1.f / 1024.f), &st, &ct);
      const float2 A1 = make_float2(1.f - st, -ct);   // 1 - iW, W=ct-i*st
      const float2 A2 = make_float2(1.f + st, ct);    // 1 + iW
      const float2 kgc = make_float2(kg.x, -kg.y);
      const float2 t1 = cmul(kf, A1), t2 = cmul(kgc, A2);
      const float2 t3 = cmul(kf, A2), t4 = cmul(kgc, A1);
      const float2 p1 = make_float2(0.5f * (t1.x + t2.x), 0.5f * (t1.y + t2.y));
      const float2 p2 = make_float2(0.5f * (t3.x + t4.x), 0.5f * (t3.y + t4.y));
      const float2 q1 = make_float2(0.5f * (t1.x - t2.x), 0.5f * (t1.y - t2.y));
      const float2 q2 = make_float2(0.5f * (t3.x - t4.x), 0.5f * (t3.y - t4.y));
      const float2 iWc = make_float2(-st, ct);        // i*conj(W)
      const float2 r1 = cmul(iWc, q1), r2 = cmul(iWc, q2);
      C1 = make_float2(p1.x + r1.x, -(p1.y + r1.y));
      C2 = make_float2(p2.x + r2.x, -(p2.y + r2.y));
      C3 = make_float2(p1.x - r1.x, p1.y - r1.y);
      C4 = make_float2(p2.x - r2.x, p2.y - r2.y);
    }
    float2* o = kep + ((size_t)c * 513 + q) * 4;
    o[0] = C1; o[1] = C2; o[2] = C3; o[3] = C4;
  }
}

// ---------------- radix-4 Stockham stage, 1024 pts, 256 threads/row ----------------
static __device__ __forceinline__ void fft_stage(
    float2* __restrict__ S, float2* __restrict__ D, int tsub, int sh,
    const float2* __restrict__ tw) {
  const int m = 1 << sh;
  const int kk = tsub & (m - 1);
  const int o = kk + ((tsub >> sh) << (sh + 2));
  const float2 a = S[PHYS(tsub)];
  const float2 b = S[PHYS(tsub + 256)];
  const float2 c = S[PHYS(tsub + 512)];
  const float2 d = S[PHYS(tsub + 768)];
  const float apcr = a.x + c.x, apci = a.y + c.y;
  const float amcr = a.x - c.x, amci = a.y - c.y;
  const float bpdr = b.x + d.x, bpdi = b.y + d.y;
  const float bmdr = b.x - d.x, bmdi = b.y - d.y;
  const float2 y0 = make_float2(apcr + bpdr, apci + bpdi);
  const float2 y2 = make_float2(apcr - bpdr, apci - bpdi);
  const float2 y1 = make_float2(amcr + bmdi, amci - bmdr);
  const float2 y3 = make_float2(amcr - bmdi, amci + bmdr);
  D[PHYS(o)] = y0;
  if (sh == 8) {  // last stage: tsub-kk == 0 -> w1 = 1, skip twiddles
    D[PHYS(o + m)] = y1;
    D[PHYS(o + 2 * m)] = y2;
    D[PHYS(o + 3 * m)] = y3;
  } else {
    const float2 w1 = tw[tsub - kk];
    const float2 w2 = cmul(w1, w1);
    const float2 w3 = cmul(w2, w1);
    D[PHYS(o + m)] = cmul(w1, y1);
    D[PHYS(o + 2 * m)] = cmul(w2, y2);
    D[PHYS(o + 3 * m)] = cmul(w3, y3);
  }
}

// ---------------- K2: rfft-conv, 2 rows/block (b, b+8), 512 threads ----------------
__global__ __launch_bounds__(512) void fft_conv(
    const float* __restrict__ u, const float2* __restrict__ kep,
    const float* __restrict__ Dv, u16* __restrict__ y) {
  __shared__ float2 bufA[2176], bufB[2176];  // 2 rows x 1088
  __shared__ float2 twl[256];
  const int bq = blockIdx.x, c = blockIdx.y;
  const int tid = threadIdx.x;
  const int half = tid >> 8, tsub = tid & 255;
  const int b = bq + 8 * half;
  if (tid < 256) {
    float s, cc;
    __sincosf(6.28318530717958647692f * (float)tid * (1.f / 1024.f), &s, &cc);
    twl[tid] = make_float2(cc, -s);
  }
  // prefetch filter coefficients (hidden under FFT #1)
  const float4* __restrict__ krow4 = (const float4*)(kep + (size_t)c * (513 * 4));
  float4 f4a[2], f4b[2];
  #pragma unroll
  for (int j = 0; j < 2; ++j) {
    const int f = tsub + 256 * j;
    f4a[j] = krow4[f * 2];
    f4b[j] = krow4[f * 2 + 1];
  }
  const float4 f4m = krow4[1024];  // q=512 row (broadcast)

  const float* __restrict__ urow = u + ((size_t)(b * 512 + c)) * 2048;
  float ur[8];
  {
    const float4 v0 = ((const float4*)urow)[tsub * 2];
    const float4 v1 = ((const float4*)urow)[tsub * 2 + 1];
    ur[0] = v0.x; ur[1] = v0.y; ur[2] = v0.z; ur[3] = v0.w;
    ur[4] = v1.x; ur[5] = v1.y; ur[6] = v1.z; ur[7] = v1.w;
  }
  float2* S = bufA + half * 1088;
  float2* Dp = bufB + half * 1088;
  #pragma unroll
  for (int j = 0; j < 4; ++j)
    S[PHYS(4 * tsub + j)] = make_float2(ur[2 * j], ur[2 * j + 1]);
  __syncthreads();

  #pragma unroll
  for (int t = 0; t < 5; ++t) {  // forward FFT of packed z
    fft_stage(S, Dp, tsub, 2 * t, twl);
    __syncthreads();
    float2* tp = S; S = Dp; Dp = tp;
  }

  // filter via 4 precomputed coeffs: D[f]=C1*conj(Zf)+C2*Zg ; D[g]=C3*Zf+C4*conj(Zg)
  #pragma unroll
  for (int j = 0; j < 2; ++j) {
    const int f = tsub + 256 * j;
    const int g = (1024 - f) & 1023;
    const float2 Zf = S[PHYS(f)], Zg = S[PHYS(g)];
    const float2 C1 = make_float2(f4a[j].x, f4a[j].y);
    const float2 C2 = make_float2(f4a[j].z, f4a[j].w);
    const float2 C3 = make_float2(f4b[j].x, f4b[j].y);
    const float2 C4 = make_float2(f4b[j].z, f4b[j].w);
    Dp[PHYS(f)] = cadd(cmul(C1, conjf2(Zf)), cmul(C2, Zg));
    Dp[PHYS(g)] = cadd(cmul(C3, Zf), cmul(C4, conjf2(Zg)));
  }
  if (tsub == 0) {
    const float2 Z5 = S[PHYS(512)];
    const float2 C1 = make_float2(f4m.x, f4m.y);
    const float2 C2 = make_float2(f4m.z, f4m.w);
    Dp[PHYS(512)] = cadd(cmul(C1, conjf2(Z5)), cmul(C2, Z5));
  }
  __syncthreads();

  {  // inverse via conj trick: data now in Dp, scratch S
    float2* tp = S; S = Dp; Dp = tp;
  }
  #pragma unroll
  for (int t = 0; t < 5; ++t) {
    fft_stage(S, Dp, tsub, 2 * t, twl);
    __syncthreads();
    float2* tp = S; S = Dp; Dp = tp;
  }

  const float Dc = Dv[c];
  u16 ov[8];
  #pragma unroll
  for (int j = 0; j < 4; ++j) {
    const float2 r = S[PHYS(4 * tsub + j)];
    const float ye = r.x + ur[2 * j] * Dc;       // kep pre-scaled by 1/2048
    const float yo = -r.y + ur[2 * j + 1] * Dc;
    ov[2 * j] = f2bf(gelu_fast(ye));
    ov[2 * j + 1] = f2bf(gelu_fast(yo));
  }
  *(u16x8*)(y + ((size_t)(b * 512 + c)) * 2048 + tsub * 8) = *(u16x8*)ov;
}

// ---------------- K2b: y (B,C,L) bf16 -> yt (B,L,C) bf16 ----------------
__global__ __launch_bounds__(256) void transpose_y(
    const u16* __restrict__ y, u16* __restrict__ yt) {
  __shared__ u16 tile[64][80];
  const int b = blockIdx.z;
  const int tb = blockIdx.x * 64;
  const int cb = blockIdx.y * 64;
  const int tid = threadIdx.x;
  {
    const int tl = (tid & 7) * 8;
    const int cl = tid >> 3;
    #pragma unroll
    for (int h = 0; h < 2; ++h) {
      const int cc = cl + h * 32;
      const u16x8 v = *(const u16x8*)(y + ((size_t)(b * 512 + cb + cc)) * 2048 + tb + tl);
      #pragma unroll
      for (int i = 0; i < 8; ++i) tile[cc][tl + i] = v[i];
    }
  }
  __syncthreads();
  {
    const int c2 = (tid & 7) * 8;
    const int t2 = tid >> 3;
    #pragma unroll
    for (int h = 0; h < 2; ++h) {
      const int tt = t2 + h * 32;
      u16 tmp[8];
      #pragma unroll
      for (int i = 0; i < 8; ++i) tmp[i] = tile[c2 + i][tt];
      *(u16x8*)(yt + ((size_t)(b * 2048 + tb + tt)) * 512 + cb + c2) = *(u16x8*)tmp;
    }
  }
}

// ---------------- K2c: W f32 -> bf16 ----------------
__global__ __launch_bounds__(256) void conv_w(const float* __restrict__ W,
                                              u16* __restrict__ Wb) {
  const int i = blockIdx.x * 256 + threadIdx.x;
  Wb[i] = f2bf(W[i]);
}

// ---------------- K3: 256x256x(K=512) 8-phase GEMM + GLU ----------------
#define FRAG_A(P, MI, S) __builtin_bit_cast(short8, *(const u16x8*)&lds[       \
    (P) * 16384 + wmh + ((MI) * 16 + lrow) * 64 + ((S) ? cs1 : cs0)])
#define FRAG_B(P, NI, S) __builtin_bit_cast(short8, *(const u16x8*)&lds[       \
    32768 + (P) * 16384 + hBh + (rB + (NI) * 16 + lrow) * 64 + ((S) ? cs1 : cs0)])

#define STAGE_A(KT, H, P) do {                                                 \
    int sr_ = m0 + (H) * 128 + wq8 + l3;                                       \
    int o0_ = (sr_ & 1) ? (512 + (sr_ >> 1)) : (sr_ >> 1);                     \
    gload_lds16(Wb + (size_t)o0_ * 512 + (KT) * 64 + csw,                      \
                lds + (P) * 16384 + (H) * 8192 + wq * 512);                    \
    sr_ += 64;                                                                 \
    int o1_ = (sr_ & 1) ? (512 + (sr_ >> 1)) : (sr_ >> 1);                     \
    gload_lds16(Wb + (size_t)o1_ * 512 + (KT) * 64 + csw,                      \
                lds + (P) * 16384 + (H) * 8192 + 4096 + wq * 512);             \
  } while (0)
#define STAGE_B(KT, H, P) do {                                                 \
    int tr_ = t0b + (H) * 128 + wq8 + l3;                                      \
    gload_lds16(yt + ((size_t)(bb * 2048 + tr_)) * 512 + (KT) * 64 + csw,      \
                lds + 32768 + (P) * 16384 + (H) * 8192 + wq * 512);            \
    gload_lds16(yt + ((size_t)(bb * 2048 + tr_ + 64)) * 512 + (KT) * 64 + csw, \
                lds + 32768 + (P) * 16384 + (H) * 8192 + 4096 + wq * 512);     \
  } while (0)

#define MFMA2(MI, NI, A0, A1)                                                  \
    acc[MI][NI] = __builtin_amdgcn_mfma_f32_16x16x32_bf16(A0, br[NI][0],       \
                                                          acc[MI][NI], 0, 0, 0); \
    acc[MI][NI] = __builtin_amdgcn_mfma_f32_16x16x32_bf16(A1, br[NI][1],       \
                                                          acc[MI][NI], 0, 0, 0);

#define PHASE_CORE(Q, READS, STAGES, VWAIT)                                    \
  {                                                                            \
    short8 a00 = FRAG_A(PP, (Q)*2 + 0, 0), a01 = FRAG_A(PP, (Q)*2 + 0, 1);     \
    short8 a10 = FRAG_A(PP, (Q)*2 + 1, 0), a11 = FRAG_A(PP, (Q)*2 + 1, 1);     \
    READS;                                                                     \
    STAGES;                                                                    \
    __builtin_amdgcn_s_barrier();                                              \
    asm volatile("s_waitcnt lgkmcnt(0)" ::: "memory");                         \
    __builtin_amdgcn_sched_barrier(0);                                         \
    __builtin_amdgcn_s_setprio(1);                                             \
    MFMA2((Q)*2 + 0, 0, a00, a01) MFMA2((Q)*2 + 0, 1, a00, a01)                \
    MFMA2((Q)*2 + 0, 2, a00, a01) MFMA2((Q)*2 + 0, 3, a00, a01)                \
    MFMA2((Q)*2 + 1, 0, a10, a11) MFMA2((Q)*2 + 1, 1, a10, a11)                \
    MFMA2((Q)*2 + 1, 2, a10, a11) MFMA2((Q)*2 + 1, 3, a10, a11)                \
    __builtin_amdgcn_s_setprio(0);                                             \
    __builtin_amdgcn_sched_barrier(0);                                         \
    VWAIT;                                                                     \
    __builtin_amdgcn_s_barrier();                                              \
  }

#define READ_B(P) do {                                                         \
    br[0][0] = FRAG_B(P, 0, 0); br[0][1] = FRAG_B(P, 0, 1);                    \
    br[1][0] = FRAG_B(P, 1, 0); br[1][1] = FRAG_B(P, 1, 1);                    \
    br[2][0] = FRAG_B(P, 2, 0); br[2][1] = FRAG_B(P, 2, 1);                    \
    br[3][0] = FRAG_B(P, 3, 0); br[3][1] = FRAG_B(P, 3, 1);                    \
  } while (0)

__global__ __launch_bounds__(512, 2) void gemm_glu(
    const u16* __restrict__ Wb, const u16* __restrict__ yt,
    const float* __restrict__ bias, float* __restrict__ out) {
  extern __shared__ __align__(16) u16 lds[];
  const int bid = blockIdx.x;
  const int wg = (bid & 7) * 64 + (bid >> 3);  // XCD swizzle (512 = 8*64)
  const int bb = wg >> 5;
  const int mt = (wg >> 3) & 3;
  const int nt = wg & 7;
  const int m0 = mt * 256;
  const int t0b = nt * 256;
  const int tid = threadIdx.x;
  const int lane = tid & 63;
  const int wq = tid >> 6;
  const int wq8 = wq * 8, l3 = lane >> 3;
  const int wm = wq >> 2, wn = wq & 3;
  const int lrow = lane & 15, lq = lane >> 4;
  const int csw = ((lane & 7) ^ l3) * 8;
  const int cs0 = ((lq ^ (lane & 7)) << 3);
  const int cs1 = (((4 + lq) ^ (lane & 7)) << 3);
  const int wmh = wm * 8192;
  const int hBh = (wn >> 1) * 8192;
  const int rB = (wn & 1) * 64;

  f32x4 acc[8][4];
  const f32x4 z4 = {0.f, 0.f, 0.f, 0.f};
  #pragma unroll
  for (int mi = 0; mi < 8; ++mi)
    #pragma unroll
    for (int ni = 0; ni < 4; ++ni) acc[mi][ni] = z4;
  short8 br[4][2];

  STAGE_A(0, 0, 0); STAGE_A(0, 1, 0);
  STAGE_B(0, 0, 0); STAGE_B(0, 1, 0);
  STAGE_B(1, 0, 1); STAGE_B(1, 1, 1);
  asm volatile("s_waitcnt vmcnt(4)" ::: "memory");
  __builtin_amdgcn_s_barrier();

  #pragma unroll
  for (int j = 0; j < 4; ++j) {
    const int e2 = 2 * j + 2, o1 = 2 * j + 1, o3 = 2 * j + 3;
    #define PP 0
    PHASE_CORE(0, READ_B(0), STAGE_A(o1, 0, 1), )
    PHASE_CORE(1, , { STAGE_A(o1, 1, 1); if (j < 3) STAGE_B(e2, 0, 0); }, )
    PHASE_CORE(2, , if (j < 3) STAGE_B(e2, 1, 0), )
    PHASE_CORE(3, , ,
               if (j < 3) { asm volatile("s_waitcnt vmcnt(4)" ::: "memory"); }
               else { asm volatile("s_waitcnt vmcnt(0)" ::: "memory"); })
    #undef PP
    #define PP 1
    PHASE_CORE(0, READ_B(1), if (j < 3) STAGE_A(e2, 0, 0), )
    PHASE_CORE(1, , if (j < 3) STAGE_A(e2, 1, 0), )
    PHASE_CORE(2, , if (j < 3) STAGE_B(o3, 0, 1), )
    PHASE_CORE(3, , if (j < 3) STAGE_B(o3, 1, 1),
               if (j < 3) { asm volatile("s_waitcnt vmcnt(4)" ::: "memory"); })
    #undef PP
  }

  #pragma unroll
  for (int mi = 0; mi < 8; ++mi) {
    const int sr0 = m0 + wm * 128 + mi * 16 + lq * 4;
    const int ch = sr0 >> 1;
    const float ba0 = bias[ch],     bg0 = bias[512 + ch];
    const float ba1 = bias[ch + 1], bg1 = bias[512 + ch + 1];
    #pragma unroll
    for (int ni = 0; ni < 4; ++ni) {
      const int t = t0b + wn * 64 + ni * 16 + (lane & 15);
      const f32x4 v = acc[mi][ni];
      const float a0 = v[0] + ba0, g0 = v[1] + bg0;
      const float a1 = v[2] + ba1, g1 = v[3] + bg1;
      out[((size_t)(bb * 512 + ch)) * 2048 + t]     = a0 * RCP(1.f + __expf(-g0));
      out[((size_t)(bb * 512 + ch + 1)) * 2048 + t] = a1 * RCP(1.f + __expf(-g1));
    }
  }
}

extern "C" void kernel_launch(void* const* d_in, const int* in_sizes, int n_in,
                              void* d_out, int out_size, void* d_ws, size_t ws_size,
                              hipStream_t stream) {
  (void)in_sizes; (void)n_in; (void)out_size; (void)ws_size;
  const float* u      = (const float*)d_in[0];
  const float* log_dt = (const float*)d_in[1];
  const float* Hr     = (const float*)d_in[2];
  const float* Hi     = (const float*)d_in[3];
  const float* Dv     = (const float*)d_in[4];
  const float* W      = (const float*)d_in[5];
  const float* bias   = (const float*)d_in[6];

  char* ws = (char*)d_ws;
  float2* kep = (float2*)(ws);                     // 512*513*4*8 = 8.4 MB
  u16*    Wb  = (u16*)  (ws + ((size_t)9 << 20));  // 1 MB
  u16*    yt  = (u16*)  (ws + ((size_t)12 << 20)); // 32 MB
  u16*    ybf = (u16*)d_out;                       // bf16 y staged in d_out[0,32MB)

  conv_w<<<dim3(2048), 256, 0, stream>>>(W, Wb);
  build_kep<<<dim3(512), 512, 0, stream>>>(log_dt, Hr, Hi, kep);
  fft_conv<<<dim3(8, 512), 512, 0, stream>>>(u, kep, Dv, ybf);
  transpose_y<<<dim3(32, 8, 16), 256, 0, stream>>>(ybf, yt);
  gemm_glu<<<dim3(512), 512, 131072, stream>>>(Wb, yt, bias, (float*)d_out);
}